// Round 3
// baseline (1597.439 us; speedup 1.0000x reference)
//
#include <hip/hip_runtime.h>
#include <hip/hip_bf16.h>

// Shapes (fixed by the reference):
//  B=16, C=512, H=W=64, HW=4096, NH=8, HD=64, QK_CH=64
//  Inputs/outputs are FP32 (reference dtype). Intermediates:
//   qkv  : bf16 in ws   [B][640][4096]  (rows 0..63 q, 64..127 k, 128..639 v)
//   At   : fp32 in ws   [B*8][64][64]   (A transposed: At[e][w] = A[w,e])
//   out_pre: fp32, written into d_out by k_apply (flat-view identity:
//            X row r of the final GEMM == d_out[r*512 .. r*512+512))
//  Then d_out is copied D2D into ws (qkv/At are dead by then) and the final
//  GEMM reads X from the ws copy, writes Y to d_out — NO in-place aliasing.
//  (Round-2 bug: in-place k_out raced — 8 oc-tile blocks read the full rows
//   that each other wrote. Fixed by the out-of-place copy.)

#define B_  16
#define C_  512
#define HW_ 4096
#define NO_ 640

typedef unsigned short u16;

__device__ __forceinline__ float bf2f(u16 u) {
    unsigned v = ((unsigned)u) << 16;
    return __uint_as_float(v);
}
__device__ __forceinline__ u16 f2bf(float f) {
    unsigned u = __float_as_uint(f);
    unsigned r = (u + 0x7FFFu + ((u >> 16) & 1u)) >> 16;  // RNE
    return (u16)r;
}

// ---------------- Kernel 1: qkv projection (fp32 in, bf16 out) ----------------
// grid (HW/1024, 640/16, B), block 256. Tile: 16 o x 1024 s. Thread: 16 o x 4 s.
__global__ __launch_bounds__(256) void k_proj(
    const float* __restrict__ x,
    const float* __restrict__ Wq, const float* __restrict__ bq,
    const float* __restrict__ Wk, const float* __restrict__ bk,
    const float* __restrict__ Wv, const float* __restrict__ bv,
    u16* __restrict__ qkv)
{
    __shared__ float Ws[16][32];
    __shared__ float Bs[16];
    const int t  = threadIdx.x;
    const int b  = blockIdx.z;
    const int o0 = blockIdx.y * 16;
    const int s  = blockIdx.x * 1024 + t * 4;
    const float* xb = x + (size_t)b * C_ * HW_;

    if (t < 16) {
        int og = o0 + t;
        float bb;
        if (og < 64)       bb = bq[og];
        else if (og < 128) bb = bk[og - 64];
        else               bb = bv[og - 128];
        Bs[t] = bb;
    }
    __syncthreads();

    float acc[16][4];
#pragma unroll
    for (int o = 0; o < 16; ++o) {
        float bb = Bs[o];
        acc[o][0] = bb; acc[o][1] = bb; acc[o][2] = bb; acc[o][3] = bb;
    }

    for (int c0 = 0; c0 < C_; c0 += 32) {
        __syncthreads();
#pragma unroll
        for (int p = 0; p < 2; ++p) {
            int idx = t + p * 256;
            int o = idx >> 5, c = idx & 31;
            int og = o0 + o;
            const float* wr;
            if (og < 64)       wr = Wq + (size_t)og * C_;
            else if (og < 128) wr = Wk + (size_t)(og - 64) * C_;
            else               wr = Wv + (size_t)(og - 128) * C_;
            Ws[o][c] = wr[c0 + c];
        }
        __syncthreads();
#pragma unroll 4
        for (int c = 0; c < 32; ++c) {
            float4 xv = *(const float4*)(xb + (size_t)(c0 + c) * HW_ + s);
#pragma unroll
            for (int o = 0; o < 16; ++o) {
                float w = Ws[o][c];
                acc[o][0] += w * xv.x; acc[o][1] += w * xv.y;
                acc[o][2] += w * xv.z; acc[o][3] += w * xv.w;
            }
        }
    }

    u16* qb = qkv + ((size_t)b * NO_ + o0) * HW_ + s;
#pragma unroll
    for (int o = 0; o < 16; ++o) {
        ushort4 ov;
        ov.x = f2bf(acc[o][0]); ov.y = f2bf(acc[o][1]);
        ov.z = f2bf(acc[o][2]); ov.w = f2bf(acc[o][3]);
        *(ushort4*)(qb + (size_t)o * HW_) = ov;
    }
}

// ---------------- Kernel 2: scores + softmax ----------------
// grid (B*NH), block 256. Thread t: d = t&63, e-group eg = t>>6 (16 e values each).
//  S[d,e] = 1/8 * sum_{l<512} q[d,l]k[e,l]
//  q[d,l] = qkv[b, 8*head + (l>>6), ((l&63)<<6) + d]
//  k[e,l] = qkv[b, 64 + 8*head + (l>>6), ((l&63)<<6) + e]
__global__ __launch_bounds__(256) void k_scores(
    const u16* __restrict__ qkv, float* __restrict__ At)
{
    __shared__ float Ks[64][4];      // K[e][l-sub]
    __shared__ float Ss[64 * 65];    // scores, padded rows
    const int t = threadIdx.x;
    const int bh = blockIdx.x;
    const int b = bh >> 3, head = bh & 7;
    const int d = t & 63, eg = t >> 6;
    const u16* qbase = qkv + ((size_t)b * NO_ + 8 * head) * HW_;
    const u16* kbase = qkv + ((size_t)b * NO_ + 64 + 8 * head) * HW_;

    float acc[16];
#pragma unroll
    for (int i = 0; i < 16; ++i) acc[i] = 0.f;

    for (int l0 = 0; l0 < 512; l0 += 4) {
        __syncthreads();
        {
            int li = t >> 6, e = t & 63;
            int l = l0 + li;
            Ks[e][li] = bf2f(kbase[(size_t)(l >> 6) * HW_ + ((l & 63) << 6) + e]);
        }
        __syncthreads();
        const u16* ql = qbase + (size_t)(l0 >> 6) * HW_ + ((l0 & 63) << 6) + d;
        float q0 = bf2f(ql[0]), q1 = bf2f(ql[64]), q2 = bf2f(ql[128]), q3 = bf2f(ql[192]);
#pragma unroll
        for (int i = 0; i < 16; ++i) {
            float4 kv = *(const float4*)Ks[eg * 16 + i];
            acc[i] += q0 * kv.x + q1 * kv.y + q2 * kv.z + q3 * kv.w;
        }
    }

    __syncthreads();
#pragma unroll
    for (int i = 0; i < 16; ++i) Ss[d * 65 + eg * 16 + i] = acc[i] * 0.125f;
    __syncthreads();

    if (t < 64) {
        int row = t;
        float m = -1e30f;
        for (int e = 0; e < 64; ++e) m = fmaxf(m, Ss[row * 65 + e]);
        float ssum = 0.f;
        for (int e = 0; e < 64; ++e) {
            float v = __expf(Ss[row * 65 + e] - m);
            Ss[row * 65 + e] = v;
            ssum += v;
        }
        float inv = 1.f / ssum;
        float* Ab = At + (size_t)bh * 4096;
        for (int e = 0; e < 64; ++e) Ab[e * 64 + row] = Ss[row * 65 + e] * inv;  // At[e][w]
    }
}

// ---------------- Kernel 3: apply attention (writes fp32 out_pre -> d_out) ----
// grid (64 a, 8 head, 16 b), block 256. Thread: w = t&63, 16 h rows.
//  out_pre[b, a*8+head, h*64+w] = sum_e A[w,e] * v[b, 64*head+a, h*64+e]
__global__ __launch_bounds__(256) void k_apply(
    const u16* __restrict__ qkv, const float* __restrict__ At,
    float* __restrict__ out_pre)
{
    __shared__ float Ats[4096];   // At[e][w]
    __shared__ float Vs[4096];    // V[h][e]
    const int t = threadIdx.x;
    const int a = blockIdx.x, head = blockIdx.y, b = blockIdx.z;
    const float* Ag = At + (size_t)(b * 8 + head) * 4096;
    const u16*   Vg = qkv + ((size_t)b * NO_ + 128 + 64 * head + a) * HW_;

#pragma unroll
    for (int i = 0; i < 4; ++i) {
        int idx = i * 1024 + t * 4;
        *(float4*)&Ats[idx] = *(const float4*)&Ag[idx];
        ushort4 vv = *(const ushort4*)&Vg[idx];
        Vs[idx]     = bf2f(vv.x); Vs[idx + 1] = bf2f(vv.y);
        Vs[idx + 2] = bf2f(vv.z); Vs[idx + 3] = bf2f(vv.w);
    }
    __syncthreads();

    const int w = t & 63, hg = t >> 6;
    float areg[64];
#pragma unroll
    for (int e = 0; e < 64; ++e) areg[e] = Ats[e * 64 + w];

    float* ob = out_pre + ((size_t)b * C_ + (a * 8 + head)) * HW_;
    for (int hh = 0; hh < 16; ++hh) {
        int h = hg * 16 + hh;
        float acc = 0.f;
#pragma unroll
        for (int e4 = 0; e4 < 16; ++e4) {
            float4 vv = *(const float4*)&Vs[h * 64 + e4 * 4];
            acc += vv.x * areg[e4 * 4] + vv.y * areg[e4 * 4 + 1]
                 + vv.z * areg[e4 * 4 + 2] + vv.w * areg[e4 * 4 + 3];
        }
        ob[h * 64 + w] = acc;
    }
}

// ---------------- Kernel 4: output linear, OUT-OF-PLACE ----------------
// Y[65536x512] = X[65536x512] @ Wo^T + bo.  X = ws copy of out_pre, Y = d_out.
// grid (512/64, 65536/64), block 256. Tile 64r x 64oc, K-chunks of 32.
__global__ __launch_bounds__(256) void k_out(
    const float* __restrict__ Xg, const float* __restrict__ Wo,
    const float* __restrict__ bo, float* __restrict__ Y)
{
    __shared__ float Xs[64][33];
    __shared__ float Wos[64][33];
    const int t = threadIdx.x;
    const int oc0 = blockIdx.x * 64;
    const size_t r0 = (size_t)blockIdx.y * 64;
    const int tx = t & 15, ty = t >> 4;

    float acc[4][4];
#pragma unroll
    for (int i = 0; i < 4; ++i)
#pragma unroll
        for (int j = 0; j < 4; ++j) acc[i][j] = 0.f;

    const int lrow = t >> 2, lcb = (t & 3) * 8;
    const float* xsrc = Xg + (r0 + lrow) * 512 + lcb;
    const float* wsrc = Wo + (size_t)(oc0 + lrow) * 512 + lcb;

    for (int c0 = 0; c0 < 512; c0 += 32) {
        __syncthreads();
        float4 a0 = *(const float4*)(xsrc + c0);
        float4 a1 = *(const float4*)(xsrc + c0 + 4);
        float4 w0 = *(const float4*)(wsrc + c0);
        float4 w1 = *(const float4*)(wsrc + c0 + 4);
        Xs[lrow][lcb + 0] = a0.x; Xs[lrow][lcb + 1] = a0.y;
        Xs[lrow][lcb + 2] = a0.z; Xs[lrow][lcb + 3] = a0.w;
        Xs[lrow][lcb + 4] = a1.x; Xs[lrow][lcb + 5] = a1.y;
        Xs[lrow][lcb + 6] = a1.z; Xs[lrow][lcb + 7] = a1.w;
        Wos[lrow][lcb + 0] = w0.x; Wos[lrow][lcb + 1] = w0.y;
        Wos[lrow][lcb + 2] = w0.z; Wos[lrow][lcb + 3] = w0.w;
        Wos[lrow][lcb + 4] = w1.x; Wos[lrow][lcb + 5] = w1.y;
        Wos[lrow][lcb + 6] = w1.z; Wos[lrow][lcb + 7] = w1.w;
        __syncthreads();
#pragma unroll 8
        for (int c = 0; c < 32; ++c) {
            float xr[4], wr[4];
#pragma unroll
            for (int i = 0; i < 4; ++i) xr[i] = Xs[ty * 4 + i][c];
#pragma unroll
            for (int j = 0; j < 4; ++j) wr[j] = Wos[tx * 4 + j][c];
#pragma unroll
            for (int i = 0; i < 4; ++i)
#pragma unroll
                for (int j = 0; j < 4; ++j) acc[i][j] += xr[i] * wr[j];
        }
    }

#pragma unroll
    for (int j = 0; j < 4; ++j) {
        float bb = bo[oc0 + tx * 4 + j];
#pragma unroll
        for (int i = 0; i < 4; ++i) acc[i][j] += bb;
    }
#pragma unroll
    for (int i = 0; i < 4; ++i) {
        float4 ov;
        ov.x = acc[i][0]; ov.y = acc[i][1]; ov.z = acc[i][2]; ov.w = acc[i][3];
        *(float4*)(Y + (r0 + ty * 4 + i) * 512 + oc0 + tx * 4) = ov;
    }
}

extern "C" void kernel_launch(void* const* d_in, const int* in_sizes, int n_in,
                              void* d_out, int out_size, void* d_ws, size_t ws_size,
                              hipStream_t stream)
{
    const float* x  = (const float*)d_in[0];
    const float* Wq = (const float*)d_in[1];
    const float* bq = (const float*)d_in[2];
    const float* Wk = (const float*)d_in[3];
    const float* bk = (const float*)d_in[4];
    const float* Wv = (const float*)d_in[5];
    const float* bv = (const float*)d_in[6];
    const float* Wo = (const float*)d_in[7];
    const float* bo = (const float*)d_in[8];
    float* out = (float*)d_out;

    char* ws = (char*)d_ws;
    u16*   qkv = (u16*)ws;                       // 16*640*4096*2 = 83,886,080 B
    float* At  = (float*)(ws + 83886080);        // 16*8*64*64*4  =  2,097,152 B
    // After k_apply, qkv and At are dead; ws[0..134217728) is reused as the
    // X copy for the final GEMM. Peak ws use: 134,217,728 B.
    float* Xcopy = (float*)ws;
    const size_t out_bytes = (size_t)B_ * C_ * HW_ * sizeof(float);  // 134,217,728

    k_proj  <<<dim3(HW_ / 1024, NO_ / 16, B_), 256, 0, stream>>>(x, Wq, bq, Wk, bk, Wv, bv, qkv);
    k_scores<<<dim3(B_ * 8), 256, 0, stream>>>(qkv, At);
    k_apply <<<dim3(64, 8, B_), 256, 0, stream>>>(qkv, At, out);
    hipMemcpyAsync(Xcopy, out, out_bytes, hipMemcpyDeviceToDevice, stream);
    k_out   <<<dim3(512 / 64, (B_ * HW_) / 64), 256, 0, stream>>>(Xcopy, Wo, bo, out);
}

// Round 4
// 562.304 us; speedup vs baseline: 2.8409x; 2.8409x over previous
//
#include <hip/hip_runtime.h>
#include <hip/hip_bf16.h>

// B=16, C=512, H=W=64, HW=4096, NH=8, HD=64, QK_CH=64.  FP32 I/O.
// Pipeline (all bf16 MFMA for the two big GEMMs, m97 structure):
//  k_wcvt : Wq|Wk|Wv -> Wcat_b16[640][512], Wo -> Wo_b16[512][512]   (ws)
//  k_x2t  : x fp32 [b][c][s] -> xT bf16 [b][s][c]                    (ws)
//  k_proj : qkv[b][o][s] = Wcat @ x[b]  (MFMA; qkv bf16 lives in d_out!)
//  k_scores: At[bh][e][w] = softmax over e of S (unchanged fp32/LDS)
//  k_apply : out_pre bf16 [b][c][hw] -> Xb16 (ws, reuses dead xT region)
//  k_out  : d_out fp32 [65536][512] = Xb16 @ Wo_b16^T + bo  (MFMA)
// ws peak: 64 MiB (xT/Xb16) + 2 MiB (At) + 1.2 MiB (weights) = 70.5 MiB.
// d_out used as qkv scratch [0,80 MiB) until k_out fully overwrites it.

#define B_  16
#define C_  512
#define HW_ 4096
#define NO_ 640

typedef unsigned short u16;
typedef __attribute__((ext_vector_type(8))) short bh8;   // 8 bf16 (4 VGPRs)
typedef __attribute__((ext_vector_type(4))) float f32x4; // MFMA C/D

__device__ __forceinline__ float bf2f(u16 u) {
    unsigned v = ((unsigned)u) << 16;
    return __uint_as_float(v);
}
__device__ __forceinline__ u16 f2bf(float f) {
    unsigned u = __float_as_uint(f);
    unsigned r = (u + 0x7FFFu + ((u >> 16) & 1u)) >> 16;  // RNE
    return (u16)r;
}

// async global->LDS, 16 B per lane; LDS dest = wave-uniform base + lane*16.
__device__ __forceinline__ void gl2lds(const u16* g, u16* l) {
    __builtin_amdgcn_global_load_lds(
        (const __attribute__((address_space(1))) unsigned int*)(const void*)g,
        (__attribute__((address_space(3))) unsigned int*)(void*)l, 16, 0, 0);
}

// ---------------- weight conversion ----------------
__global__ __launch_bounds__(256) void k_wcvt(
    const float* __restrict__ Wq, const float* __restrict__ Wk,
    const float* __restrict__ Wv, const float* __restrict__ Wo,
    u16* __restrict__ Wcat, u16* __restrict__ Wob)
{
    int idx = blockIdx.x * 256 + threadIdx.x;
    if (idx < NO_ * C_) {
        int o = idx >> 9, c = idx & 511;
        float v = (o < 64) ? Wq[o * C_ + c]
                : (o < 128) ? Wk[(o - 64) * C_ + c]
                : Wv[(size_t)(o - 128) * C_ + c];
        Wcat[idx] = f2bf(v);
    }
    int idx2 = idx - NO_ * C_;
    if (idx2 >= 0 && idx2 < C_ * C_) Wob[idx2] = f2bf(Wo[idx2]);
}

// ---------------- x transpose: [b][c][s] fp32 -> [b][s][c] bf16 ----------------
__global__ __launch_bounds__(256) void k_x2t(
    const float* __restrict__ x, u16* __restrict__ xT)
{
    __shared__ u16 T[32][33];
    const int t = threadIdx.x;
    const int s0 = blockIdx.x * 32, c0 = blockIdx.y * 32, b = blockIdx.z;
    const float* xb = x + ((size_t)b * C_ + c0) * HW_ + s0;
    {
        int c = t >> 3, s4 = (t & 7) * 4;
        float4 v = *(const float4*)(xb + (size_t)c * HW_ + s4);
        T[s4][c] = f2bf(v.x); T[s4 + 1][c] = f2bf(v.y);
        T[s4 + 2][c] = f2bf(v.z); T[s4 + 3][c] = f2bf(v.w);
    }
    __syncthreads();
    {
        int s = t >> 3, cb = (t & 7) * 4;
        ushort4 o;
        o.x = T[s][cb]; o.y = T[s][cb + 1]; o.z = T[s][cb + 2]; o.w = T[s][cb + 3];
        *(ushort4*)(xT + ((size_t)b * HW_ + s0 + s) * C_ + c0 + cb) = o;
    }
}

// ---------------- k_proj (MFMA): qkv[b][o][s] = Wcat @ x[b] + bias ----------------
// A = Wcat[640][512] ([m][k]), B = xT[b][4096][512] ([n][k]).  Tile 128x128, BK=32.
__global__ __launch_bounds__(256) void k_proj(
    const u16* __restrict__ Wcat, const u16* __restrict__ xT,
    const float* __restrict__ bq, const float* __restrict__ bk,
    const float* __restrict__ bv, u16* __restrict__ qkv)
{
    __shared__ u16 As[128 * 32];
    __shared__ u16 Bs[128 * 32];
    const int t = threadIdx.x;
    const int lane = t & 63, w = t >> 6;
    const int q = lane >> 4, ln = lane & 15;
    const int n0 = blockIdx.x * 128, m0 = blockIdx.y * 128, b = blockIdx.z;
    const u16* xTb = xT + (size_t)b * HW_ * C_;
    const int wm = (w >> 1) * 64, wn = (w & 1) * 64;
    const int srow = lane >> 2, scol = (lane & 3) * 8;

    f32x4 acc[4][4];
#pragma unroll
    for (int i = 0; i < 4; ++i)
#pragma unroll
        for (int j = 0; j < 4; ++j) acc[i][j] = (f32x4){0.f, 0.f, 0.f, 0.f};

    for (int k0 = 0; k0 < C_; k0 += 32) {
        __syncthreads();
#pragma unroll
        for (int i = 0; i < 2; ++i) {
            int rowblk = (i * 4 + w) * 16;
            gl2lds(Wcat + (size_t)(m0 + rowblk + srow) * C_ + k0 + scol, &As[rowblk * 32]);
            gl2lds(xTb  + (size_t)(n0 + rowblk + srow) * C_ + k0 + scol, &Bs[rowblk * 32]);
        }
        __syncthreads();
        bh8 af[4], bfv[4];
#pragma unroll
        for (int i = 0; i < 4; ++i) af[i]  = *(const bh8*)&As[(wm + i * 16 + ln) * 32 + q * 8];
#pragma unroll
        for (int j = 0; j < 4; ++j) bfv[j] = *(const bh8*)&Bs[(wn + j * 16 + ln) * 32 + q * 8];
#pragma unroll
        for (int i = 0; i < 4; ++i)
#pragma unroll
            for (int j = 0; j < 4; ++j)
                acc[i][j] = __builtin_amdgcn_mfma_f32_16x16x32_bf16(af[i], bfv[j], acc[i][j], 0, 0, 0);
    }

    u16* qb = qkv + (size_t)b * NO_ * HW_;
#pragma unroll
    for (int i = 0; i < 4; ++i) {
#pragma unroll
        for (int r = 0; r < 4; ++r) {
            int o = m0 + wm + i * 16 + q * 4 + r;
            float bia = (o < 64) ? bq[o] : (o < 128) ? bk[o - 64] : bv[o - 128];
#pragma unroll
            for (int j = 0; j < 4; ++j) {
                int s = n0 + wn + j * 16 + ln;
                qb[(size_t)o * HW_ + s] = f2bf(acc[i][j][r] + bia);
            }
        }
    }
}

// ---------------- k_scores (unchanged structure) ----------------
__global__ __launch_bounds__(256) void k_scores(
    const u16* __restrict__ qkv, float* __restrict__ At)
{
    __shared__ float Ks[64][4];
    __shared__ float Ss[64 * 65];
    const int t = threadIdx.x;
    const int bh = blockIdx.x;
    const int b = bh >> 3, head = bh & 7;
    const int d = t & 63, eg = t >> 6;
    const u16* qbase = qkv + ((size_t)b * NO_ + 8 * head) * HW_;
    const u16* kbase = qkv + ((size_t)b * NO_ + 64 + 8 * head) * HW_;

    float acc[16];
#pragma unroll
    for (int i = 0; i < 16; ++i) acc[i] = 0.f;

    for (int l0 = 0; l0 < 512; l0 += 4) {
        __syncthreads();
        {
            int li = t >> 6, e = t & 63;
            int l = l0 + li;
            Ks[e][li] = bf2f(kbase[(size_t)(l >> 6) * HW_ + ((l & 63) << 6) + e]);
        }
        __syncthreads();
        const u16* ql = qbase + (size_t)(l0 >> 6) * HW_ + ((l0 & 63) << 6) + d;
        float q0 = bf2f(ql[0]), q1 = bf2f(ql[64]), q2 = bf2f(ql[128]), q3 = bf2f(ql[192]);
#pragma unroll
        for (int i = 0; i < 16; ++i) {
            float4 kv = *(const float4*)Ks[eg * 16 + i];
            acc[i] += q0 * kv.x + q1 * kv.y + q2 * kv.z + q3 * kv.w;
        }
    }

    __syncthreads();
#pragma unroll
    for (int i = 0; i < 16; ++i) Ss[d * 65 + eg * 16 + i] = acc[i] * 0.125f;
    __syncthreads();

    if (t < 64) {
        int row = t;
        float m = -1e30f;
        for (int e = 0; e < 64; ++e) m = fmaxf(m, Ss[row * 65 + e]);
        float ssum = 0.f;
        for (int e = 0; e < 64; ++e) {
            float v = __expf(Ss[row * 65 + e] - m);
            Ss[row * 65 + e] = v;
            ssum += v;
        }
        float inv = 1.f / ssum;
        float* Ab = At + (size_t)bh * 4096;
        for (int e = 0; e < 64; ++e) Ab[e * 64 + row] = Ss[row * 65 + e] * inv;  // At[e][w]
    }
}

// ---------------- k_apply: out_pre bf16 [b][c][hw] -> Xb16 ----------------
__global__ __launch_bounds__(256) void k_apply(
    const u16* __restrict__ qkv, const float* __restrict__ At,
    u16* __restrict__ Xb16)
{
    __shared__ float Ats[4096];   // At[e][w]
    __shared__ float Vs[4096];    // V[h][e]
    const int t = threadIdx.x;
    const int a = blockIdx.x, head = blockIdx.y, b = blockIdx.z;
    const float* Ag = At + (size_t)(b * 8 + head) * 4096;
    const u16*   Vg = qkv + ((size_t)b * NO_ + 128 + 64 * head + a) * HW_;

#pragma unroll
    for (int i = 0; i < 4; ++i) {
        int idx = i * 1024 + t * 4;
        *(float4*)&Ats[idx] = *(const float4*)&Ag[idx];
        ushort4 vv = *(const ushort4*)&Vg[idx];
        Vs[idx]     = bf2f(vv.x); Vs[idx + 1] = bf2f(vv.y);
        Vs[idx + 2] = bf2f(vv.z); Vs[idx + 3] = bf2f(vv.w);
    }
    __syncthreads();

    const int w = t & 63, hg = t >> 6;
    float areg[64];
#pragma unroll
    for (int e = 0; e < 64; ++e) areg[e] = Ats[e * 64 + w];

    u16* ob = Xb16 + ((size_t)b * C_ + (a * 8 + head)) * HW_;
    for (int hh = 0; hh < 16; ++hh) {
        int h = hg * 16 + hh;
        float acc = 0.f;
#pragma unroll
        for (int e4 = 0; e4 < 16; ++e4) {
            float4 vv = *(const float4*)&Vs[h * 64 + e4 * 4];
            acc += vv.x * areg[e4 * 4] + vv.y * areg[e4 * 4 + 1]
                 + vv.z * areg[e4 * 4 + 2] + vv.w * areg[e4 * 4 + 3];
        }
        ob[h * 64 + w] = f2bf(acc);
    }
}

// ---------------- k_out (MFMA): Y = Xb16 @ Wo_b16^T + bo, fp32 out ----------------
// A = Xb16[65536][512] ([m][k]), B = Wo_b16[512][512] ([n][k]). Tile 128x128, BK=32.
__global__ __launch_bounds__(256) void k_out(
    const u16* __restrict__ Xg, const u16* __restrict__ Wob,
    const float* __restrict__ bo, float* __restrict__ Y)
{
    __shared__ u16 As[128 * 32];
    __shared__ u16 Bs[128 * 32];
    const int t = threadIdx.x;
    const int lane = t & 63, w = t >> 6;
    const int q = lane >> 4, ln = lane & 15;
    const int n0 = blockIdx.x * 128;
    const size_t r0 = (size_t)blockIdx.y * 128;
    const int wm = (w >> 1) * 64, wn = (w & 1) * 64;
    const int srow = lane >> 2, scol = (lane & 3) * 8;

    f32x4 acc[4][4];
#pragma unroll
    for (int i = 0; i < 4; ++i)
#pragma unroll
        for (int j = 0; j < 4; ++j) acc[i][j] = (f32x4){0.f, 0.f, 0.f, 0.f};

    for (int k0 = 0; k0 < C_; k0 += 32) {
        __syncthreads();
#pragma unroll
        for (int i = 0; i < 2; ++i) {
            int rowblk = (i * 4 + w) * 16;
            gl2lds(Xg  + (r0 + rowblk + srow) * C_ + k0 + scol, &As[rowblk * 32]);
            gl2lds(Wob + (size_t)(n0 + rowblk + srow) * C_ + k0 + scol, &Bs[rowblk * 32]);
        }
        __syncthreads();
        bh8 af[4], bfv[4];
#pragma unroll
        for (int i = 0; i < 4; ++i) af[i]  = *(const bh8*)&As[(wm + i * 16 + ln) * 32 + q * 8];
#pragma unroll
        for (int j = 0; j < 4; ++j) bfv[j] = *(const bh8*)&Bs[(wn + j * 16 + ln) * 32 + q * 8];
#pragma unroll
        for (int i = 0; i < 4; ++i)
#pragma unroll
            for (int j = 0; j < 4; ++j)
                acc[i][j] = __builtin_amdgcn_mfma_f32_16x16x32_bf16(af[i], bfv[j], acc[i][j], 0, 0, 0);
    }

#pragma unroll
    for (int i = 0; i < 4; ++i) {
#pragma unroll
        for (int r = 0; r < 4; ++r) {
            size_t row = r0 + wm + i * 16 + q * 4 + r;
#pragma unroll
            for (int j = 0; j < 4; ++j) {
                int col = n0 + wn + j * 16 + ln;
                Y[row * C_ + col] = acc[i][j][r] + bo[col];
            }
        }
    }
}

extern "C" void kernel_launch(void* const* d_in, const int* in_sizes, int n_in,
                              void* d_out, int out_size, void* d_ws, size_t ws_size,
                              hipStream_t stream)
{
    const float* x  = (const float*)d_in[0];
    const float* Wq = (const float*)d_in[1];
    const float* bq = (const float*)d_in[2];
    const float* Wk = (const float*)d_in[3];
    const float* bk = (const float*)d_in[4];
    const float* Wv = (const float*)d_in[5];
    const float* bv = (const float*)d_in[6];
    const float* Wo = (const float*)d_in[7];
    const float* bo = (const float*)d_in[8];

    char* ws = (char*)d_ws;
    u16*   xT   = (u16*)ws;                              // [0, 64 MiB)
    u16*   Xb16 = (u16*)ws;                              // reuses xT after k_proj
    float* At   = (float*)(ws + 67108864);               // 2 MiB
    u16*   Wcat = (u16*)(ws + 67108864 + 2097152);       // 655,360 B
    u16*   Wob  = (u16*)(ws + 67108864 + 2097152 + 655360); // 524,288 B
    u16*   qkv  = (u16*)d_out;                           // 80 MiB scratch in d_out
    float* Y    = (float*)d_out;

    k_wcvt  <<<dim3((NO_ * C_ + C_ * C_ + 255) / 256), 256, 0, stream>>>(Wq, Wk, Wv, Wo, Wcat, Wob);
    k_x2t   <<<dim3(HW_ / 32, C_ / 32, B_), 256, 0, stream>>>(x, xT);
    k_proj  <<<dim3(HW_ / 128, NO_ / 128, B_), 256, 0, stream>>>(Wcat, xT, bq, bk, bv, qkv);
    k_scores<<<dim3(B_ * 8), 256, 0, stream>>>(qkv, At);
    k_apply <<<dim3(64, 8, B_), 256, 0, stream>>>(qkv, At, Xb16);
    k_out   <<<dim3(C_ / 128, (B_ * HW_) / 128), 256, 0, stream>>>(Xb16, Wob, bo, Y);
}

// Round 5
// 472.616 us; speedup vs baseline: 3.3800x; 1.1898x over previous
//
#include <hip/hip_runtime.h>
#include <hip/hip_bf16.h>

// B=16, C=512, H=W=64, HW=4096, NH=8, HD=64, QK_CH=64.  FP32 I/O.
// Pipeline:
//  k_wcvt : Wq|Wk|Wv -> Wcat_b16[640][512], Wo -> Wo_b16[512][512]   (ws)
//  k_x2t  : x fp32 [b][c][s] -> xT bf16 [b][s][c]                    (ws)
//  k_proj : qkv[b][o][s] = Wcat @ x[b]  (MFMA; qkv bf16 lives in d_out)
//  k_scores: Aw[bh][w][e] = softmax_e(S)[w,e]  (bf16, e-contiguous)
//  k_apply : MFMA 64x64x64 per (b,head,h); fragments straight from global
//            (both operands e-contiguous; no LDS, no barriers).
//            out_pre bf16 -> Xb16 (ws, reuses dead xT region)
//  k_out  : d_out fp32 [65536][512] = Xb16 @ Wo_b16^T + bo  (MFMA)
// ws peak: 64 MiB (xT/Xb16) + 2 MiB (Aw) + 1.2 MiB (weights).
// d_out used as qkv scratch [0,80 MiB) until k_out fully overwrites it.

#define B_  16
#define C_  512
#define HW_ 4096
#define NO_ 640

typedef unsigned short u16;
typedef __attribute__((ext_vector_type(8))) short bh8;   // 8 bf16 (4 VGPRs)
typedef __attribute__((ext_vector_type(4))) float f32x4; // MFMA C/D

__device__ __forceinline__ float bf2f(u16 u) {
    unsigned v = ((unsigned)u) << 16;
    return __uint_as_float(v);
}
__device__ __forceinline__ u16 f2bf(float f) {
    unsigned u = __float_as_uint(f);
    unsigned r = (u + 0x7FFFu + ((u >> 16) & 1u)) >> 16;  // RNE
    return (u16)r;
}

// async global->LDS, 16 B per lane; LDS dest = wave-uniform base + lane*16.
__device__ __forceinline__ void gl2lds(const u16* g, u16* l) {
    __builtin_amdgcn_global_load_lds(
        (const __attribute__((address_space(1))) unsigned int*)(const void*)g,
        (__attribute__((address_space(3))) unsigned int*)(void*)l, 16, 0, 0);
}

// ---------------- weight conversion ----------------
__global__ __launch_bounds__(256) void k_wcvt(
    const float* __restrict__ Wq, const float* __restrict__ Wk,
    const float* __restrict__ Wv, const float* __restrict__ Wo,
    u16* __restrict__ Wcat, u16* __restrict__ Wob)
{
    int idx = blockIdx.x * 256 + threadIdx.x;
    if (idx < NO_ * C_) {
        int o = idx >> 9, c = idx & 511;
        float v = (o < 64) ? Wq[o * C_ + c]
                : (o < 128) ? Wk[(o - 64) * C_ + c]
                : Wv[(size_t)(o - 128) * C_ + c];
        Wcat[idx] = f2bf(v);
    }
    int idx2 = idx - NO_ * C_;
    if (idx2 >= 0 && idx2 < C_ * C_) Wob[idx2] = f2bf(Wo[idx2]);
}

// ---------------- x transpose: [b][c][s] fp32 -> [b][s][c] bf16 ----------------
__global__ __launch_bounds__(256) void k_x2t(
    const float* __restrict__ x, u16* __restrict__ xT)
{
    __shared__ u16 T[32][33];
    const int t = threadIdx.x;
    const int s0 = blockIdx.x * 32, c0 = blockIdx.y * 32, b = blockIdx.z;
    const float* xb = x + ((size_t)b * C_ + c0) * HW_ + s0;
    {
        int c = t >> 3, s4 = (t & 7) * 4;
        float4 v = *(const float4*)(xb + (size_t)c * HW_ + s4);
        T[s4][c] = f2bf(v.x); T[s4 + 1][c] = f2bf(v.y);
        T[s4 + 2][c] = f2bf(v.z); T[s4 + 3][c] = f2bf(v.w);
    }
    __syncthreads();
    {
        int s = t >> 3, cb = (t & 7) * 4;
        ushort4 o;
        o.x = T[s][cb]; o.y = T[s][cb + 1]; o.z = T[s][cb + 2]; o.w = T[s][cb + 3];
        *(ushort4*)(xT + ((size_t)b * HW_ + s0 + s) * C_ + c0 + cb) = o;
    }
}

// ---------------- k_proj (MFMA): qkv[b][o][s] = Wcat @ x[b] + bias ----------------
// A = Wcat[640][512] ([m][k]), B = xT[b][4096][512] ([n][k]).  Tile 128x128, BK=32.
__global__ __launch_bounds__(256) void k_proj(
    const u16* __restrict__ Wcat, const u16* __restrict__ xT,
    const float* __restrict__ bq, const float* __restrict__ bk,
    const float* __restrict__ bv, u16* __restrict__ qkv)
{
    __shared__ u16 As[128 * 32];
    __shared__ u16 Bs[128 * 32];
    const int t = threadIdx.x;
    const int lane = t & 63, w = t >> 6;
    const int q = lane >> 4, ln = lane & 15;
    const int n0 = blockIdx.x * 128, m0 = blockIdx.y * 128, b = blockIdx.z;
    const u16* xTb = xT + (size_t)b * HW_ * C_;
    const int wm = (w >> 1) * 64, wn = (w & 1) * 64;
    const int srow = lane >> 2, scol = (lane & 3) * 8;

    f32x4 acc[4][4];
#pragma unroll
    for (int i = 0; i < 4; ++i)
#pragma unroll
        for (int j = 0; j < 4; ++j) acc[i][j] = (f32x4){0.f, 0.f, 0.f, 0.f};

    for (int k0 = 0; k0 < C_; k0 += 32) {
        __syncthreads();
#pragma unroll
        for (int i = 0; i < 2; ++i) {
            int rowblk = (i * 4 + w) * 16;
            gl2lds(Wcat + (size_t)(m0 + rowblk + srow) * C_ + k0 + scol, &As[rowblk * 32]);
            gl2lds(xTb  + (size_t)(n0 + rowblk + srow) * C_ + k0 + scol, &Bs[rowblk * 32]);
        }
        __syncthreads();
        bh8 af[4], bfv[4];
#pragma unroll
        for (int i = 0; i < 4; ++i) af[i]  = *(const bh8*)&As[(wm + i * 16 + ln) * 32 + q * 8];
#pragma unroll
        for (int j = 0; j < 4; ++j) bfv[j] = *(const bh8*)&Bs[(wn + j * 16 + ln) * 32 + q * 8];
#pragma unroll
        for (int i = 0; i < 4; ++i)
#pragma unroll
            for (int j = 0; j < 4; ++j)
                acc[i][j] = __builtin_amdgcn_mfma_f32_16x16x32_bf16(af[i], bfv[j], acc[i][j], 0, 0, 0);
    }

    u16* qb = qkv + (size_t)b * NO_ * HW_;
#pragma unroll
    for (int i = 0; i < 4; ++i) {
#pragma unroll
        for (int r = 0; r < 4; ++r) {
            int o = m0 + wm + i * 16 + q * 4 + r;
            float bia = (o < 64) ? bq[o] : (o < 128) ? bk[o - 64] : bv[o - 128];
#pragma unroll
            for (int j = 0; j < 4; ++j) {
                int s = n0 + wn + j * 16 + ln;
                qb[(size_t)o * HW_ + s] = f2bf(acc[i][j][r] + bia);
            }
        }
    }
}

// ---------------- k_scores: S + softmax -> Aw[bh][w][e] bf16 ----------------
__global__ __launch_bounds__(256) void k_scores(
    const u16* __restrict__ qkv, u16* __restrict__ Aw)
{
    __shared__ float Ks[64][4];
    __shared__ float Ss[64 * 65];
    const int t = threadIdx.x;
    const int bh = blockIdx.x;
    const int b = bh >> 3, head = bh & 7;
    const int d = t & 63, eg = t >> 6;
    const u16* qbase = qkv + ((size_t)b * NO_ + 8 * head) * HW_;
    const u16* kbase = qkv + ((size_t)b * NO_ + 64 + 8 * head) * HW_;

    float acc[16];
#pragma unroll
    for (int i = 0; i < 16; ++i) acc[i] = 0.f;

    for (int l0 = 0; l0 < 512; l0 += 4) {
        __syncthreads();
        {
            int li = t >> 6, e = t & 63;
            int l = l0 + li;
            Ks[e][li] = bf2f(kbase[(size_t)(l >> 6) * HW_ + ((l & 63) << 6) + e]);
        }
        __syncthreads();
        const u16* ql = qbase + (size_t)(l0 >> 6) * HW_ + ((l0 & 63) << 6) + d;
        float q0 = bf2f(ql[0]), q1 = bf2f(ql[64]), q2 = bf2f(ql[128]), q3 = bf2f(ql[192]);
#pragma unroll
        for (int i = 0; i < 16; ++i) {
            float4 kv = *(const float4*)Ks[eg * 16 + i];
            acc[i] += q0 * kv.x + q1 * kv.y + q2 * kv.z + q3 * kv.w;
        }
    }

    __syncthreads();
#pragma unroll
    for (int i = 0; i < 16; ++i) Ss[d * 65 + eg * 16 + i] = acc[i] * 0.125f;
    __syncthreads();

    if (t < 64) {
        int row = t;               // row = w coordinate
        float m = -1e30f;
        for (int e = 0; e < 64; ++e) m = fmaxf(m, Ss[row * 65 + e]);
        float ssum = 0.f;
        for (int e = 0; e < 64; ++e) {
            float v = __expf(Ss[row * 65 + e] - m);
            Ss[row * 65 + e] = v;
            ssum += v;
        }
        float inv = 1.f / ssum;
        u16* Ab = Aw + (size_t)bh * 4096;
        for (int e = 0; e < 64; ++e) Ab[row * 64 + e] = f2bf(Ss[row * 65 + e] * inv);
    }
}

// ---------------- k_apply (MFMA, no LDS): out_pre = A @ V per (b,head,h) ------
// grid (8 hg, 8 head, 16 b), 4 waves/block; wave wv handles h = hg*8 + wv*2 + {0,1}.
// D[a][w'] = sum_e V[a][e] * Aw[w'][e]; both operands e-contiguous in global.
__global__ __launch_bounds__(256) void k_apply(
    const u16* __restrict__ qkv, const u16* __restrict__ Aw,
    u16* __restrict__ Xb16)
{
    const int t = threadIdx.x;
    const int lane = t & 63, wv = t >> 6;
    const int q = lane >> 4, ln = lane & 15;
    const int hg = blockIdx.x, head = blockIdx.y, b = blockIdx.z;
    const u16* Ag = Aw + (size_t)(b * 8 + head) * 4096;
    const u16* Vg = qkv + ((size_t)b * NO_ + 128 + 64 * head) * HW_;
    u16* ob = Xb16 + ((size_t)b * C_ + head) * HW_;   // + a*8*HW_ later

    // B fragments (A matrix), shared across both h iterations.
    bh8 bfv[4][2];
#pragma unroll
    for (int j = 0; j < 4; ++j)
#pragma unroll
        for (int ks = 0; ks < 2; ++ks)
            bfv[j][ks] = *(const bh8*)(Ag + (size_t)(j * 16 + ln) * 64 + ks * 32 + q * 8);

#pragma unroll
    for (int hi = 0; hi < 2; ++hi) {
        const int h = hg * 8 + wv * 2 + hi;
        // A fragments (V_h), straight from global: rows a=i*16+ln, k=e.
        bh8 af[4][2];
#pragma unroll
        for (int i = 0; i < 4; ++i)
#pragma unroll
            for (int ks = 0; ks < 2; ++ks)
                af[i][ks] = *(const bh8*)(Vg + (size_t)(i * 16 + ln) * HW_ + h * 64 + ks * 32 + q * 8);

        f32x4 acc[4][4];
#pragma unroll
        for (int i = 0; i < 4; ++i)
#pragma unroll
            for (int j = 0; j < 4; ++j) acc[i][j] = (f32x4){0.f, 0.f, 0.f, 0.f};
#pragma unroll
        for (int ks = 0; ks < 2; ++ks)
#pragma unroll
            for (int i = 0; i < 4; ++i)
#pragma unroll
                for (int j = 0; j < 4; ++j)
                    acc[i][j] = __builtin_amdgcn_mfma_f32_16x16x32_bf16(af[i][ks], bfv[j][ks], acc[i][j], 0, 0, 0);

        // D: a = i*16 + q*4 + r, w' = j*16 + ln; channel c = a*8 + head.
#pragma unroll
        for (int i = 0; i < 4; ++i)
#pragma unroll
            for (int r = 0; r < 4; ++r) {
                int a = i * 16 + q * 4 + r;
                u16* orow = ob + (size_t)a * 8 * HW_ + h * 64;
#pragma unroll
                for (int j = 0; j < 4; ++j)
                    orow[j * 16 + ln] = f2bf(acc[i][j][r]);
            }
    }
}

// ---------------- k_out (MFMA): Y = Xb16 @ Wo_b16^T + bo, fp32 out ----------------
// A = Xb16[65536][512] ([m][k]), B = Wo_b16[512][512] ([n][k]). Tile 128x128, BK=32.
__global__ __launch_bounds__(256) void k_out(
    const u16* __restrict__ Xg, const u16* __restrict__ Wob,
    const float* __restrict__ bo, float* __restrict__ Y)
{
    __shared__ u16 As[128 * 32];
    __shared__ u16 Bs[128 * 32];
    const int t = threadIdx.x;
    const int lane = t & 63, w = t >> 6;
    const int q = lane >> 4, ln = lane & 15;
    const int n0 = blockIdx.x * 128;
    const size_t r0 = (size_t)blockIdx.y * 128;
    const int wm = (w >> 1) * 64, wn = (w & 1) * 64;
    const int srow = lane >> 2, scol = (lane & 3) * 8;

    f32x4 acc[4][4];
#pragma unroll
    for (int i = 0; i < 4; ++i)
#pragma unroll
        for (int j = 0; j < 4; ++j) acc[i][j] = (f32x4){0.f, 0.f, 0.f, 0.f};

    for (int k0 = 0; k0 < C_; k0 += 32) {
        __syncthreads();
#pragma unroll
        for (int i = 0; i < 2; ++i) {
            int rowblk = (i * 4 + w) * 16;
            gl2lds(Xg  + (r0 + rowblk + srow) * C_ + k0 + scol, &As[rowblk * 32]);
            gl2lds(Wob + (size_t)(n0 + rowblk + srow) * C_ + k0 + scol, &Bs[rowblk * 32]);
        }
        __syncthreads();
        bh8 af[4], bfv[4];
#pragma unroll
        for (int i = 0; i < 4; ++i) af[i]  = *(const bh8*)&As[(wm + i * 16 + ln) * 32 + q * 8];
#pragma unroll
        for (int j = 0; j < 4; ++j) bfv[j] = *(const bh8*)&Bs[(wn + j * 16 + ln) * 32 + q * 8];
#pragma unroll
        for (int i = 0; i < 4; ++i)
#pragma unroll
            for (int j = 0; j < 4; ++j)
                acc[i][j] = __builtin_amdgcn_mfma_f32_16x16x32_bf16(af[i], bfv[j], acc[i][j], 0, 0, 0);
    }

#pragma unroll
    for (int i = 0; i < 4; ++i) {
#pragma unroll
        for (int r = 0; r < 4; ++r) {
            size_t row = r0 + wm + i * 16 + q * 4 + r;
#pragma unroll
            for (int j = 0; j < 4; ++j) {
                int col = n0 + wn + j * 16 + ln;
                Y[row * C_ + col] = acc[i][j][r] + bo[col];
            }
        }
    }
}

extern "C" void kernel_launch(void* const* d_in, const int* in_sizes, int n_in,
                              void* d_out, int out_size, void* d_ws, size_t ws_size,
                              hipStream_t stream)
{
    const float* x  = (const float*)d_in[0];
    const float* Wq = (const float*)d_in[1];
    const float* bq = (const float*)d_in[2];
    const float* Wk = (const float*)d_in[3];
    const float* bk = (const float*)d_in[4];
    const float* Wv = (const float*)d_in[5];
    const float* bv = (const float*)d_in[6];
    const float* Wo = (const float*)d_in[7];
    const float* bo = (const float*)d_in[8];

    char* ws = (char*)d_ws;
    u16*   xT   = (u16*)ws;                              // [0, 64 MiB)
    u16*   Xb16 = (u16*)ws;                              // reuses xT after k_proj
    u16*   Aw   = (u16*)(ws + 67108864);                 // 1 MiB used (2 MiB reserved)
    u16*   Wcat = (u16*)(ws + 67108864 + 2097152);       // 655,360 B
    u16*   Wob  = (u16*)(ws + 67108864 + 2097152 + 655360); // 524,288 B
    u16*   qkv  = (u16*)d_out;                           // 80 MiB scratch in d_out
    float* Y    = (float*)d_out;

    k_wcvt  <<<dim3((NO_ * C_ + C_ * C_ + 255) / 256), 256, 0, stream>>>(Wq, Wk, Wv, Wo, Wcat, Wob);
    k_x2t   <<<dim3(HW_ / 32, C_ / 32, B_), 256, 0, stream>>>(x, xT);
    k_proj  <<<dim3(HW_ / 128, NO_ / 128, B_), 256, 0, stream>>>(Wcat, xT, bq, bk, bv, qkv);
    k_scores<<<dim3(B_ * 8), 256, 0, stream>>>(qkv, Aw);
    k_apply <<<dim3(8, 8, B_), 256, 0, stream>>>(qkv, Aw, Xb16);
    k_out   <<<dim3(C_ / 128, (B_ * HW_) / 128), 256, 0, stream>>>(Xb16, Wob, bo, Y);
}